// Round 8
// baseline (275.402 us; speedup 1.0000x reference)
//
#include <hip/hip_runtime.h>
#include <cstdint>
#include <cstddef>

// GIN: B=32, N=1024, FIN=128, H1=64, H2=32, OUT=10. adj binary, ~1% dense.
// Round-12: revert r10/r11 fusion (neutral). Base = round-7 (269.15, best,
// reproduced twice). ONE change: gathA/gathB go 2 -> 4 nodes/wave (blocks
// 4096 -> 2048). Latency-bound kernels (gathB: 12% VALUBusy, 0.8% HBM):
// 4 independent gather streams/wave (32 loads in flight/round), 2x MLP per
// weight round-trip, SAME dead-load ratio (r8's widen-per-node mistake
// avoided). Per-node loop structure, slot mapping (t&7 / t parity), and fma
// trees identical to round-7 -> bit-exact.
// Kept: u16 CSR, atomicMax readout + separate k_fin (r6 lesson: no per-block
// device fences), no-LDS scanproj, 2-rows/wave scan, XCD swizzle,
// reg->LDS weight prefetch, self-load hoist.

#define CAP 64

typedef float v4f __attribute__((ext_vector_type(4)));

__device__ __forceinline__ float rl(float x, int l) {   // wave-uniform lane bcast
  return __int_as_float(__builtin_amdgcn_readlane(__float_as_int(x), l));
}

// ---------------- fused: proj (u = x@W1a) + scan (adj -> CSR u16) ------------
// NO __shared__ anywhere in this kernel: scan occupancy must not pay for it.
__global__ __launch_bounds__(256) void k_scanproj(
    const float* __restrict__ x, const float* __restrict__ W1a,
    float* __restrict__ u,
    const float* __restrict__ adj, unsigned short* __restrict__ nbr,
    int* __restrict__ deg, unsigned* __restrict__ g_u32) {
  int lane = threadIdx.x & 63;
  int wid  = threadIdx.x >> 6;
  if (blockIdx.x == 0) {
    // init readout atomicMax keys (key 0 < encode(any float); always beaten)
    #pragma unroll
    for (int i = 0; i < 4; ++i) g_u32[threadIdx.x * 4 + i] = 0u;
  }
  if (blockIdx.x < 1024) {
    // ---- proj: u = x @ W1a, 8 rows/wave; W1a via L1 (exactly 32 KB) ----
    int row0 = (blockIdx.x * 4 + wid) * 8;
    row0 = __builtin_amdgcn_readfirstlane(row0);
    const float* xr = x + (size_t)row0 * 128;
    float acc[8] = {0, 0, 0, 0, 0, 0, 0, 0};
    for (int kc = 0; kc < 32; ++kc) {
      v4f xv[8];
      #pragma unroll
      for (int r = 0; r < 8; ++r)
        xv[r] = *(const v4f*)(xr + r * 128 + kc * 4);
      #pragma unroll
      for (int j = 0; j < 4; ++j) {
        float w = W1a[(kc * 4 + j) * 64 + lane];   // L1-hit after warmup
        #pragma unroll
        for (int r = 0; r < 8; ++r)
          acc[r] = fmaf(xv[r][j], w, acc[r]);
      }
    }
    #pragma unroll
    for (int r = 0; r < 8; ++r)
      u[(size_t)(row0 + r) * 64 + lane] = acc[r];
  } else {
    // ---- scan: one wave per TWO 4 KB adj rows; 8 loads in flight, two
    //      independent extraction chains (ILP) ----
    int node = (blockIdx.x - 1024) * 8 + wid * 2;  // 4096 blocks -> 32768 rows
    const v4f* arow0 = (const v4f*)(adj + (size_t)node * 1024);
    const v4f* arow1 = (const v4f*)(adj + ((size_t)node + 1) * 1024);
    unsigned short* outp0 = nbr + node * CAP;
    unsigned short* outp1 = outp0 + CAP;
    v4f a0[4], a1[4];
    #pragma unroll
    for (int c = 0; c < 4; ++c) {
      a0[c] = __builtin_nontemporal_load(arow0 + c * 64 + lane);
      a1[c] = __builtin_nontemporal_load(arow1 + c * 64 + lane);
    }
    int cnt0 = 0, cnt1 = 0;
    #pragma unroll
    for (int c = 0; c < 4; ++c) {
      #pragma unroll
      for (int comp = 0; comp < 4; ++comp) {
        int idx = ((c * 64 + lane) << 2) + comp;
        bool h0 = (a0[c][comp] != 0.0f);
        bool h1 = (a1[c][comp] != 0.0f);
        unsigned long long m0 = __ballot(h0);
        unsigned long long m1 = __ballot(h1);
        if (h0) {
          int below = __builtin_amdgcn_mbcnt_hi(
              (unsigned)(m0 >> 32),
              __builtin_amdgcn_mbcnt_lo((unsigned)m0, 0));
          int pos = cnt0 + below;
          if (pos < CAP) outp0[pos] = (unsigned short)idx;
        }
        if (h1) {
          int below = __builtin_amdgcn_mbcnt_hi(
              (unsigned)(m1 >> 32),
              __builtin_amdgcn_mbcnt_lo((unsigned)m1, 0));
          int pos = cnt1 + below;
          if (pos < CAP) outp1[pos] = (unsigned short)idx;
        }
        cnt0 += __popcll(m0);
        cnt1 += __popcll(m1);
      }
    }
    if (lane == 0) {
      deg[node]     = cnt0 < CAP ? cnt0 : CAP;
      deg[node + 1] = cnt1 < CAP ? cnt1 : CAP;
    }
  }
}

// ---------------- layer A: gather u via CSR + MLP -> v (4 nodes/wave) --------
// XCD swizzle: block i -> xcd=i&7, j=i>>3; batch b = xcd + 8*(j&3);
// chunk w = j>>2 (0..63), 16 nodes/block. u footprint 1 MB/XCD (L2-resident).
// 4 gather streams/wave, 32 loads in flight/round. Weights global->reg at
// top, reg->LDS after gathers (latency overlap).
__global__ __launch_bounds__(256) void k_gathA(
    const float* __restrict__ u, const unsigned short* __restrict__ nbr,
    const int* __restrict__ deg, const float* __restrict__ mask,
    const float* __restrict__ b1a, const float* __restrict__ W2a,
    const float* __restrict__ b2a, const float* __restrict__ W1b,
    float* __restrict__ v) {
  __shared__ float sW2[64 * 64];    // 16 KB
  __shared__ float sW1b[64 * 32];   // 8 KB
  float wr2[16], wr1[8];
  #pragma unroll
  for (int i = 0; i < 16; ++i) wr2[i] = W2a[threadIdx.x + i * 256];
  #pragma unroll
  for (int i = 0; i < 8; ++i)  wr1[i] = W1b[threadIdx.x + i * 256];
  int lane = threadIdx.x & 63;
  int f = lane & 31, hh = lane >> 5;
  float ba1 = b1a[lane], ba2 = b2a[lane];
  int i = blockIdx.x, wid = threadIdx.x >> 6;
  int xcd = i & 7, j = i >> 3;
  int b = xcd + 8 * (j & 3);
  int w = j >> 2;                                  // 0..63
  int n0 = b * 1024 + w * 16 + wid * 4;            // 4 consecutive nodes
  const float* ub = u + (size_t)b * 1024 * 64;
  int dd[4], nl[4];
  float self[4];
  #pragma unroll
  for (int q = 0; q < 4; ++q) {
    dd[q]   = deg[n0 + q];
    nl[q]   = nbr[(n0 + q) * CAP + lane];
    self[q] = ub[((n0 + q) & 1023) * 64 + lane];   // issue early
  }
  float s[4][8] = {};
  int dmax = dd[0] > dd[1] ? dd[0] : dd[1];
  dmax = dd[2] > dmax ? dd[2] : dmax;
  dmax = dd[3] > dmax ? dd[3] : dmax;
  int rounds = (dmax + 7) >> 3;
  for (int rr = 0; rr < rounds; ++rr) {
    int base = rr << 3;
    #pragma unroll
    for (int i2 = 0; i2 < 8; ++i2) {
      int t = base + i2;
      #pragma unroll
      for (int q = 0; q < 4; ++q) {                // 4 independent streams
        int jq = __builtin_amdgcn_readlane(nl[q], t);
        bool ok = t < dd[q];
        jq = ok ? jq : 0;
        float vq = ub[jq * 64 + lane];             // L2-local 256 B gathers
        s[q][i2] += ok ? vq : 0.0f;                // same slot map as round-7
      }
    }
  }
  float acc[4];
  #pragma unroll
  for (int q = 0; q < 4; ++q)
    acc[q] = self[q] + (((s[q][0]+s[q][1])+(s[q][2]+s[q][3]))
                     + ((s[q][4]+s[q][5])+(s[q][6]+s[q][7])));
  // stage weights to LDS now (loads issued at kernel top have long completed)
  #pragma unroll
  for (int t = 0; t < 16; ++t) sW2[threadIdx.x + t * 256] = wr2[t];
  #pragma unroll
  for (int t = 0; t < 8; ++t)  sW1b[threadIdx.x + t * 256] = wr1[t];
  __syncthreads();
  float r[4];
  #pragma unroll
  for (int q = 0; q < 4; ++q) r[q] = fmaxf(acc[q] + ba1, 0.0f);
  float A[4][4] = {};
  #pragma unroll
  for (int k = 0; k < 64; k += 4) {
    float w0 = sW2[(k    ) * 64 + lane];
    float w1 = sW2[(k + 1) * 64 + lane];
    float w2 = sW2[(k + 2) * 64 + lane];
    float w3 = sW2[(k + 3) * 64 + lane];
    #pragma unroll
    for (int q = 0; q < 4; ++q) {
      A[q][0] = fmaf(rl(r[q], k    ), w0, A[q][0]);
      A[q][1] = fmaf(rl(r[q], k + 1), w1, A[q][1]);
      A[q][2] = fmaf(rl(r[q], k + 2), w2, A[q][2]);
      A[q][3] = fmaf(rl(r[q], k + 3), w3, A[q][3]);
    }
  }
  float h2[4];
  #pragma unroll
  for (int q = 0; q < 4; ++q)
    h2[q] = (ba2 + ((A[q][0] + A[q][1]) + (A[q][2] + A[q][3]))) * mask[n0 + q];
  float p0[4] = {}, p1[4] = {};
  #pragma unroll
  for (int k0 = 0; k0 < 32; k0 += 2) {
    float w0 = sW1b[(hh * 32 + k0    ) * 32 + f];
    float w1 = sW1b[(hh * 32 + k0 + 1) * 32 + f];
    #pragma unroll
    for (int q = 0; q < 4; ++q) {
      p0[q] = fmaf(__shfl(h2[q], hh * 32 + k0    ), w0, p0[q]);
      p1[q] = fmaf(__shfl(h2[q], hh * 32 + k0 + 1), w1, p1[q]);
    }
  }
  #pragma unroll
  for (int q = 0; q < 4; ++q) {
    float vp = p0[q] + p1[q];
    vp += __shfl_xor(vp, 32);
    if (hh == 0) v[(n0 + q) * 32 + f] = vp;
  }
}

// ---------------- layer B: gather v + MLP + fused readout (4 nodes/wave) -----
// Same XCD swizzle (v: 512 KB/XCD in L2; nbr re-hit from scan). h3 never
// written. Block feature-max -> ordered-u32 atomicMax into g_u32 (monotone
// key). NO fence/counter tail (round-6 lesson: 4096 device fences = +61 us).
__global__ __launch_bounds__(256) void k_gathB(
    const float* __restrict__ v, const unsigned short* __restrict__ nbr,
    const int* __restrict__ deg, const float* __restrict__ mask,
    const float* __restrict__ b1b, const float* __restrict__ W2b,
    const float* __restrict__ b2b, unsigned* __restrict__ g_u32) {
  __shared__ float sW2b[32 * 32];   // 4 KB
  __shared__ float wred[4][32];
  float wrb[4];
  #pragma unroll
  for (int i = 0; i < 4; ++i) wrb[i] = W2b[threadIdx.x + i * 256];
  int lane = threadIdx.x & 63;
  int f = lane & 31, hh = lane >> 5;
  float bb1 = b1b[f], bb2 = b2b[f];
  int i = blockIdx.x, wid = threadIdx.x >> 6;
  int xcd = i & 7, j = i >> 3;
  int b = xcd + 8 * (j & 3);
  int w = j >> 2;                                  // 0..63
  int n0 = b * 1024 + w * 16 + wid * 4;            // 4 consecutive nodes
  const float* vb = v + (size_t)b * 1024 * 32;
  int dd[4], nl[4];
  float selfv[4];
  #pragma unroll
  for (int q = 0; q < 4; ++q) {
    dd[q]    = deg[n0 + q];
    nl[q]    = nbr[(n0 + q) * CAP + lane];
    selfv[q] = vb[((n0 + q) & 1023) * 32 + f];     // issue early
  }
  float s[4][8] = {};
  int dmax = dd[0] > dd[1] ? dd[0] : dd[1];
  dmax = dd[2] > dmax ? dd[2] : dmax;
  dmax = dd[3] > dmax ? dd[3] : dmax;
  int rounds = (dmax + 15) >> 4;
  for (int rr = 0; rr < rounds; ++rr) {
    int base = rr << 4;
    #pragma unroll
    for (int i2 = 0; i2 < 8; ++i2) {
      int t = base + (i2 << 1) + hh;               // halves alternate nbrs
      #pragma unroll
      for (int q = 0; q < 4; ++q) {                // 4 independent streams
        int jq = __shfl(nl[q], t);
        bool ok = t < dd[q];
        jq = ok ? jq : 0;
        float vv = vb[jq * 32 + f];
        s[q][i2] += ok ? vv : 0.0f;                // same slot map as round-7
      }
    }
  }
  float acc[4];
  #pragma unroll
  for (int q = 0; q < 4; ++q) {
    acc[q] = (((s[q][0]+s[q][1])+(s[q][2]+s[q][3]))
            + ((s[q][4]+s[q][5])+(s[q][6]+s[q][7])));
    acc[q] += __shfl_xor(acc[q], 32);
  }
  // stage weights to LDS (loads issued at kernel top)
  #pragma unroll
  for (int t = 0; t < 4; ++t) sW2b[threadIdx.x + t * 256] = wrb[t];
  __syncthreads();
  float r[4];
  #pragma unroll
  for (int q = 0; q < 4; ++q)
    r[q] = fmaxf(selfv[q] + acc[q] + bb1, 0.0f);
  float A[4][4] = {};
  #pragma unroll
  for (int k = 0; k < 32; k += 4) {
    float w0 = sW2b[(k    ) * 32 + f];
    float w1 = sW2b[(k + 1) * 32 + f];
    float w2 = sW2b[(k + 2) * 32 + f];
    float w3 = sW2b[(k + 3) * 32 + f];
    #pragma unroll
    for (int q = 0; q < 4; ++q) {
      A[q][0] = fmaf(rl(r[q], k    ), w0, A[q][0]);
      A[q][1] = fmaf(rl(r[q], k + 1), w1, A[q][1]);
      A[q][2] = fmaf(rl(r[q], k + 2), w2, A[q][2]);
      A[q][3] = fmaf(rl(r[q], k + 3), w3, A[q][3]);
    }
  }
  float o[4];
  #pragma unroll
  for (int q = 0; q < 4; ++q)
    o[q] = (bb2 + ((A[q][0] + A[q][1]) + (A[q][2] + A[q][3]))) * mask[n0 + q];
  // per-wave max of the 4 nodes (o identical on both halves), then block max
  float m = fmaxf(fmaxf(o[0], o[1]), fmaxf(o[2], o[3]));
  if (hh == 0) wred[wid][f] = m;
  __syncthreads();
  if (threadIdx.x < 32) {
    float mm = fmaxf(fmaxf(wred[0][threadIdx.x], wred[1][threadIdx.x]),
                     fmaxf(wred[2][threadIdx.x], wred[3][threadIdx.x]));
    unsigned bu  = __float_as_uint(mm);
    unsigned key = bu ^ ((unsigned)((int)bu >> 31) | 0x80000000u);
    atomicMax(&g_u32[(b << 5) + threadIdx.x], key);   // device-scope, exact max
  }
}

// ---------------- final: decode g keys; out = g@Wfc + bfc (one block) --------
__global__ __launch_bounds__(320) void k_fin(
    const unsigned* __restrict__ g_u32, const float* __restrict__ Wfc,
    const float* __restrict__ bfc, float* __restrict__ out) {
  __shared__ float g[1024];
  int t = threadIdx.x;
  if (t < 256) {
    #pragma unroll
    for (int i = 0; i < 4; ++i) {
      unsigned key  = g_u32[t * 4 + i];
      unsigned flip = (key >> 31) ? 0x80000000u : 0xFFFFFFFFu;
      g[t * 4 + i] = __uint_as_float(key ^ flip);
    }
  }
  __syncthreads();
  int b = t / 10, o = t - b * 10;                  // 320 threads = 32x10 outs
  if (b < 32) {
    float acc = bfc[o];
    #pragma unroll
    for (int k = 0; k < 32; ++k)                   // same fma order as before
      acc = fmaf(g[b * 32 + k], Wfc[k * 10 + o], acc);
    out[b * 10 + o] = acc;
  }
}

extern "C" void kernel_launch(void* const* d_in, const int* in_sizes, int n_in,
                              void* d_out, int out_size, void* d_ws, size_t ws_size,
                              hipStream_t stream) {
  const float* x    = (const float*)d_in[0];
  const float* adj  = (const float*)d_in[1];
  const float* mask = (const float*)d_in[2];
  const float* W1a  = (const float*)d_in[3];
  const float* b1a  = (const float*)d_in[4];
  const float* W2a  = (const float*)d_in[5];
  const float* b2a  = (const float*)d_in[6];
  const float* W1b  = (const float*)d_in[7];
  const float* b1b  = (const float*)d_in[8];
  const float* W2b  = (const float*)d_in[9];
  const float* b2b  = (const float*)d_in[10];
  const float* Wfc  = (const float*)d_in[11];
  const float* bfc  = (const float*)d_in[12];
  float* out = (float*)d_out;

  // ws: u[0,8M) v[8M,12M) nbr16[12M,16M) deg[16M,+128K) g_u32[17M,+4K)
  char* ws = (char*)d_ws;
  float*          u     = (float*)(ws);
  float*          v     = (float*)(ws + (8u  << 20));
  unsigned short* nbr   = (unsigned short*)(ws + (12u << 20));
  int*            deg   = (int*)  (ws + (16u << 20));
  unsigned*       g_u32 = (unsigned*)(ws + (17u << 20));

  hipLaunchKernelGGL(k_scanproj, dim3(5120), dim3(256), 0, stream,
                     x, W1a, u, adj, nbr, deg, g_u32);
  hipLaunchKernelGGL(k_gathA,    dim3(2048), dim3(256), 0, stream,
                     u, nbr, deg, mask, b1a, W2a, b2a, W1b, v);
  hipLaunchKernelGGL(k_gathB,    dim3(2048), dim3(256), 0, stream,
                     v, nbr, deg, mask, b1b, W2b, b2b, g_u32);
  hipLaunchKernelGGL(k_fin,      dim3(1),    dim3(320), 0, stream,
                     g_u32, Wfc, bfc, out);
}

// Round 9
// 269.443 us; speedup vs baseline: 1.0221x; 1.0221x over previous
//
#include <hip/hip_runtime.h>
#include <cstdint>
#include <cstddef>

// GIN: B=32, N=1024, FIN=128, H1=64, H2=32, OUT=10. adj binary, ~1% dense.
// Round-13: RESTORE round-7 (best, 269.0/269.15 reproduced twice).
// Ledger of failed attacks on the ~19us kernel headroom (75us warm kernels
// vs ~56us roofline): r8 g2l+16wide +10; r10/r11 scan fusion +5; r12
// 4-nodes/wave +6. The gather kernels are latency-bound on the in-wave
// readlane->load->sum chain; wave-count/ILP levers all regressed. ~154us of
// the 269 window is harness poison fills + gaps (untouchable).
// Structure: scanproj (proj u=x@W1a 8rows/wave + 2-row/wave ballot scan ->
// u16 CSR), gathA (2 nodes/wave, L2-resident 256B gathers, reg->LDS weight
// prefetch), gathB (+ fused readout via ordered-u32 atomicMax; r6 lesson:
// no per-block device fences), tiny k_fin decode+FC.

#define CAP 64

typedef float v4f __attribute__((ext_vector_type(4)));

__device__ __forceinline__ float rl(float x, int l) {   // wave-uniform lane bcast
  return __int_as_float(__builtin_amdgcn_readlane(__float_as_int(x), l));
}

// ---------------- fused: proj (u = x@W1a) + scan (adj -> CSR u16) ------------
// NO __shared__ anywhere in this kernel: scan occupancy must not pay for it.
__global__ __launch_bounds__(256) void k_scanproj(
    const float* __restrict__ x, const float* __restrict__ W1a,
    float* __restrict__ u,
    const float* __restrict__ adj, unsigned short* __restrict__ nbr,
    int* __restrict__ deg, unsigned* __restrict__ g_u32) {
  int lane = threadIdx.x & 63;
  int wid  = threadIdx.x >> 6;
  if (blockIdx.x == 0) {
    // init readout atomicMax keys (key 0 < encode(any float); always beaten)
    #pragma unroll
    for (int i = 0; i < 4; ++i) g_u32[threadIdx.x * 4 + i] = 0u;
  }
  if (blockIdx.x < 1024) {
    // ---- proj: u = x @ W1a, 8 rows/wave; W1a via L1 (exactly 32 KB) ----
    int row0 = (blockIdx.x * 4 + wid) * 8;
    row0 = __builtin_amdgcn_readfirstlane(row0);
    const float* xr = x + (size_t)row0 * 128;
    float acc[8] = {0, 0, 0, 0, 0, 0, 0, 0};
    for (int kc = 0; kc < 32; ++kc) {
      v4f xv[8];
      #pragma unroll
      for (int r = 0; r < 8; ++r)
        xv[r] = *(const v4f*)(xr + r * 128 + kc * 4);
      #pragma unroll
      for (int j = 0; j < 4; ++j) {
        float w = W1a[(kc * 4 + j) * 64 + lane];   // L1-hit after warmup
        #pragma unroll
        for (int r = 0; r < 8; ++r)
          acc[r] = fmaf(xv[r][j], w, acc[r]);
      }
    }
    #pragma unroll
    for (int r = 0; r < 8; ++r)
      u[(size_t)(row0 + r) * 64 + lane] = acc[r];
  } else {
    // ---- scan: one wave per TWO 4 KB adj rows; 8 loads in flight, two
    //      independent extraction chains (ILP) ----
    int node = (blockIdx.x - 1024) * 8 + wid * 2;  // 4096 blocks -> 32768 rows
    const v4f* arow0 = (const v4f*)(adj + (size_t)node * 1024);
    const v4f* arow1 = (const v4f*)(adj + ((size_t)node + 1) * 1024);
    unsigned short* outp0 = nbr + node * CAP;
    unsigned short* outp1 = outp0 + CAP;
    v4f a0[4], a1[4];
    #pragma unroll
    for (int c = 0; c < 4; ++c) {
      a0[c] = __builtin_nontemporal_load(arow0 + c * 64 + lane);
      a1[c] = __builtin_nontemporal_load(arow1 + c * 64 + lane);
    }
    int cnt0 = 0, cnt1 = 0;
    #pragma unroll
    for (int c = 0; c < 4; ++c) {
      #pragma unroll
      for (int comp = 0; comp < 4; ++comp) {
        int idx = ((c * 64 + lane) << 2) + comp;
        bool h0 = (a0[c][comp] != 0.0f);
        bool h1 = (a1[c][comp] != 0.0f);
        unsigned long long m0 = __ballot(h0);
        unsigned long long m1 = __ballot(h1);
        if (h0) {
          int below = __builtin_amdgcn_mbcnt_hi(
              (unsigned)(m0 >> 32),
              __builtin_amdgcn_mbcnt_lo((unsigned)m0, 0));
          int pos = cnt0 + below;
          if (pos < CAP) outp0[pos] = (unsigned short)idx;
        }
        if (h1) {
          int below = __builtin_amdgcn_mbcnt_hi(
              (unsigned)(m1 >> 32),
              __builtin_amdgcn_mbcnt_lo((unsigned)m1, 0));
          int pos = cnt1 + below;
          if (pos < CAP) outp1[pos] = (unsigned short)idx;
        }
        cnt0 += __popcll(m0);
        cnt1 += __popcll(m1);
      }
    }
    if (lane == 0) {
      deg[node]     = cnt0 < CAP ? cnt0 : CAP;
      deg[node + 1] = cnt1 < CAP ? cnt1 : CAP;
    }
  }
}

// ---------------- layer A: gather u via CSR + MLP -> v ----------------
// XCD swizzle: block i -> xcd=i&7, j=i>>3; batch b = xcd + 8*(j&3);
// within-batch chunk w = j>>2 (0..127). Each XCD sees 4 batches -> u
// footprint 1 MB (L2-resident). 2 nodes/wave, 16 gathers in flight.
// Weights go global->reg BEFORE gathers, reg->LDS AFTER (latency overlap).
__global__ __launch_bounds__(256) void k_gathA(
    const float* __restrict__ u, const unsigned short* __restrict__ nbr,
    const int* __restrict__ deg, const float* __restrict__ mask,
    const float* __restrict__ b1a, const float* __restrict__ W2a,
    const float* __restrict__ b2a, const float* __restrict__ W1b,
    float* __restrict__ v) {
  __shared__ float sW2[64 * 64];    // 16 KB
  __shared__ float sW1b[64 * 32];   // 8 KB
  float wr2[16], wr1[8];
  #pragma unroll
  for (int i = 0; i < 16; ++i) wr2[i] = W2a[threadIdx.x + i * 256];
  #pragma unroll
  for (int i = 0; i < 8; ++i)  wr1[i] = W1b[threadIdx.x + i * 256];
  int lane = threadIdx.x & 63;
  int f = lane & 31, hh = lane >> 5;
  float ba1 = b1a[lane], ba2 = b2a[lane];
  int i = blockIdx.x, wid = threadIdx.x >> 6;
  int xcd = i & 7, j = i >> 3;
  int b = xcd + 8 * (j & 3);
  int w = j >> 2;                                  // 0..127
  int n0 = b * 1024 + w * 8 + wid * 2, n1 = n0 + 1;
  const float* ub = u + (size_t)b * 1024 * 64;
  int d0 = deg[n0], d1 = deg[n1];
  int nl0 = nbr[n0 * CAP + lane], nl1 = nbr[n1 * CAP + lane];
  float self0 = ub[(n0 & 1023) * 64 + lane];       // issue early: overlaps loop
  float self1 = ub[(n1 & 1023) * 64 + lane];
  float s0[8] = {0,0,0,0,0,0,0,0}, s1[8] = {0,0,0,0,0,0,0,0};
  int dmax = d0 > d1 ? d0 : d1;
  int rounds = (dmax + 7) >> 3;
  for (int rr = 0; rr < rounds; ++rr) {
    int base = rr << 3;
    #pragma unroll
    for (int i2 = 0; i2 < 8; ++i2) {
      int t = base + i2;
      int j0 = __builtin_amdgcn_readlane(nl0, t);
      int j1 = __builtin_amdgcn_readlane(nl1, t);
      bool ok0 = t < d0, ok1 = t < d1;
      j0 = ok0 ? j0 : 0;  j1 = ok1 ? j1 : 0;
      float v0 = ub[j0 * 64 + lane];               // L2-local 256 B gathers
      float v1 = ub[j1 * 64 + lane];
      s0[i2] += ok0 ? v0 : 0.0f;
      s1[i2] += ok1 ? v1 : 0.0f;
    }
  }
  float acc0 = self0
             + (((s0[0]+s0[1])+(s0[2]+s0[3]))+((s0[4]+s0[5])+(s0[6]+s0[7])));
  float acc1 = self1
             + (((s1[0]+s1[1])+(s1[2]+s1[3]))+((s1[4]+s1[5])+(s1[6]+s1[7])));
  // stage weights to LDS now (loads issued at kernel top have long completed)
  #pragma unroll
  for (int t = 0; t < 16; ++t) sW2[threadIdx.x + t * 256] = wr2[t];
  #pragma unroll
  for (int t = 0; t < 8; ++t)  sW1b[threadIdx.x + t * 256] = wr1[t];
  __syncthreads();
  float r0 = fmaxf(acc0 + ba1, 0.0f);
  float r1 = fmaxf(acc1 + ba1, 0.0f);
  float a0=0,a1=0,a2=0,a3=0, c0=0,c1=0,c2=0,c3=0;
  #pragma unroll
  for (int k = 0; k < 64; k += 4) {
    float w0 = sW2[(k    ) * 64 + lane];
    float w1 = sW2[(k + 1) * 64 + lane];
    float w2 = sW2[(k + 2) * 64 + lane];
    float w3 = sW2[(k + 3) * 64 + lane];
    a0 = fmaf(rl(r0, k    ), w0, a0);  c0 = fmaf(rl(r1, k    ), w0, c0);
    a1 = fmaf(rl(r0, k + 1), w1, a1);  c1 = fmaf(rl(r1, k + 1), w1, c1);
    a2 = fmaf(rl(r0, k + 2), w2, a2);  c2 = fmaf(rl(r1, k + 2), w2, c2);
    a3 = fmaf(rl(r0, k + 3), w3, a3);  c3 = fmaf(rl(r1, k + 3), w3, c3);
  }
  float h20 = (ba2 + ((a0 + a1) + (a2 + a3))) * mask[n0];
  float h21 = (ba2 + ((c0 + c1) + (c2 + c3))) * mask[n1];
  float p00=0,p01=0, p10=0,p11=0;
  #pragma unroll
  for (int k0 = 0; k0 < 32; k0 += 2) {
    float w0 = sW1b[(hh * 32 + k0    ) * 32 + f];
    float w1 = sW1b[(hh * 32 + k0 + 1) * 32 + f];
    p00 = fmaf(__shfl(h20, hh * 32 + k0    ), w0, p00);
    p01 = fmaf(__shfl(h20, hh * 32 + k0 + 1), w1, p01);
    p10 = fmaf(__shfl(h21, hh * 32 + k0    ), w0, p10);
    p11 = fmaf(__shfl(h21, hh * 32 + k0 + 1), w1, p11);
  }
  float vp0 = p00 + p01;  vp0 += __shfl_xor(vp0, 32);
  float vp1 = p10 + p11;  vp1 += __shfl_xor(vp1, 32);
  if (hh == 0) {
    v[n0 * 32 + f] = vp0;
    v[n1 * 32 + f] = vp1;
  }
}

// ---------------- layer B: gather v via CSR + MLP + fused readout ------------
// Same XCD swizzle (v: 512 KB/XCD in L2; nbr re-hit from gathA). h3 never
// written. Block feature-max -> ordered-u32 atomicMax into g_u32 (monotone
// key: positive -> u|0x80000000, negative -> ~u). Exact. NO fence/counter
// tail (round-6 lesson: 4096 device fences = +61 us).
__global__ __launch_bounds__(256) void k_gathB(
    const float* __restrict__ v, const unsigned short* __restrict__ nbr,
    const int* __restrict__ deg, const float* __restrict__ mask,
    const float* __restrict__ b1b, const float* __restrict__ W2b,
    const float* __restrict__ b2b, unsigned* __restrict__ g_u32) {
  __shared__ float sW2b[32 * 32];   // 4 KB
  __shared__ float wred[4][32];
  float wrb[4];
  #pragma unroll
  for (int i = 0; i < 4; ++i) wrb[i] = W2b[threadIdx.x + i * 256];
  int lane = threadIdx.x & 63;
  int f = lane & 31, hh = lane >> 5;
  float bb1 = b1b[f], bb2 = b2b[f];
  int i = blockIdx.x, wid = threadIdx.x >> 6;
  int xcd = i & 7, j = i >> 3;
  int b = xcd + 8 * (j & 3);
  int w = j >> 2;                                  // 0..127
  int n0 = b * 1024 + w * 8 + wid * 2, n1 = n0 + 1;
  const float* vb = v + (size_t)b * 1024 * 32;
  int d0 = deg[n0], d1 = deg[n1];
  int nl0 = nbr[n0 * CAP + lane], nl1 = nbr[n1 * CAP + lane];
  float selfv0 = vb[(n0 & 1023) * 32 + f];         // issue early
  float selfv1 = vb[(n1 & 1023) * 32 + f];
  float s0[8] = {0,0,0,0,0,0,0,0}, s1[8] = {0,0,0,0,0,0,0,0};
  int dmax = d0 > d1 ? d0 : d1;
  int rounds = (dmax + 15) >> 4;
  for (int rr = 0; rr < rounds; ++rr) {
    int base = rr << 4;
    #pragma unroll
    for (int i2 = 0; i2 < 8; ++i2) {
      int t = base + (i2 << 1) + hh;               // halves alternate nbrs
      int j0 = __shfl(nl0, t);
      int j1 = __shfl(nl1, t);
      bool ok0 = t < d0, ok1 = t < d1;
      j0 = ok0 ? j0 : 0;  j1 = ok1 ? j1 : 0;
      float v0 = vb[j0 * 32 + f];
      float v1 = vb[j1 * 32 + f];
      s0[i2] += ok0 ? v0 : 0.0f;
      s1[i2] += ok1 ? v1 : 0.0f;
    }
  }
  float acc0 = ((s0[0]+s0[1])+(s0[2]+s0[3]))+((s0[4]+s0[5])+(s0[6]+s0[7]));
  float acc1 = ((s1[0]+s1[1])+(s1[2]+s1[3]))+((s1[4]+s1[5])+(s1[6]+s1[7]));
  acc0 += __shfl_xor(acc0, 32);
  acc1 += __shfl_xor(acc1, 32);
  // stage weights to LDS (loads issued at kernel top)
  #pragma unroll
  for (int t = 0; t < 4; ++t) sW2b[threadIdx.x + t * 256] = wrb[t];
  __syncthreads();
  float r0 = fmaxf(selfv0 + acc0 + bb1, 0.0f);
  float r1 = fmaxf(selfv1 + acc1 + bb1, 0.0f);
  float a0=0,a1=0,a2=0,a3=0, c0=0,c1=0,c2=0,c3=0;
  #pragma unroll
  for (int k = 0; k < 32; k += 4) {
    float w0 = sW2b[(k    ) * 32 + f];
    float w1 = sW2b[(k + 1) * 32 + f];
    float w2 = sW2b[(k + 2) * 32 + f];
    float w3 = sW2b[(k + 3) * 32 + f];
    a0 = fmaf(rl(r0, k    ), w0, a0);  c0 = fmaf(rl(r1, k    ), w0, c0);
    a1 = fmaf(rl(r0, k + 1), w1, a1);  c1 = fmaf(rl(r1, k + 1), w1, c1);
    a2 = fmaf(rl(r0, k + 2), w2, a2);  c2 = fmaf(rl(r1, k + 2), w2, c2);
    a3 = fmaf(rl(r0, k + 3), w3, a3);  c3 = fmaf(rl(r1, k + 3), w3, c3);
  }
  float o0 = (bb2 + ((a0 + a1) + (a2 + a3))) * mask[n0];
  float o1 = (bb2 + ((c0 + c1) + (c2 + c3))) * mask[n1];
  // per-wave max of the 2 nodes (o identical on both halves), then block max
  float m = fmaxf(o0, o1);
  if (hh == 0) wred[wid][f] = m;
  __syncthreads();
  if (threadIdx.x < 32) {
    float mm = fmaxf(fmaxf(wred[0][threadIdx.x], wred[1][threadIdx.x]),
                     fmaxf(wred[2][threadIdx.x], wred[3][threadIdx.x]));
    unsigned bu  = __float_as_uint(mm);
    unsigned key = bu ^ ((unsigned)((int)bu >> 31) | 0x80000000u);
    atomicMax(&g_u32[(b << 5) + threadIdx.x], key);   // device-scope, exact max
  }
}

// ---------------- final: decode g keys; out = g@Wfc + bfc (one block) --------
__global__ __launch_bounds__(320) void k_fin(
    const unsigned* __restrict__ g_u32, const float* __restrict__ Wfc,
    const float* __restrict__ bfc, float* __restrict__ out) {
  __shared__ float g[1024];
  int t = threadIdx.x;
  if (t < 256) {
    #pragma unroll
    for (int i = 0; i < 4; ++i) {
      unsigned key  = g_u32[t * 4 + i];
      unsigned flip = (key >> 31) ? 0x80000000u : 0xFFFFFFFFu;
      g[t * 4 + i] = __uint_as_float(key ^ flip);
    }
  }
  __syncthreads();
  int b = t / 10, o = t - b * 10;                  // 320 threads = 32x10 outs
  if (b < 32) {
    float acc = bfc[o];
    #pragma unroll
    for (int k = 0; k < 32; ++k)                   // same fma order as before
      acc = fmaf(g[b * 32 + k], Wfc[k * 10 + o], acc);
    out[b * 10 + o] = acc;
  }
}

extern "C" void kernel_launch(void* const* d_in, const int* in_sizes, int n_in,
                              void* d_out, int out_size, void* d_ws, size_t ws_size,
                              hipStream_t stream) {
  const float* x    = (const float*)d_in[0];
  const float* adj  = (const float*)d_in[1];
  const float* mask = (const float*)d_in[2];
  const float* W1a  = (const float*)d_in[3];
  const float* b1a  = (const float*)d_in[4];
  const float* W2a  = (const float*)d_in[5];
  const float* b2a  = (const float*)d_in[6];
  const float* W1b  = (const float*)d_in[7];
  const float* b1b  = (const float*)d_in[8];
  const float* W2b  = (const float*)d_in[9];
  const float* b2b  = (const float*)d_in[10];
  const float* Wfc  = (const float*)d_in[11];
  const float* bfc  = (const float*)d_in[12];
  float* out = (float*)d_out;

  // ws: u[0,8M) v[8M,12M) nbr16[12M,16M) deg[16M,+128K) g_u32[17M,+4K)
  char* ws = (char*)d_ws;
  float*          u     = (float*)(ws);
  float*          v     = (float*)(ws + (8u  << 20));
  unsigned short* nbr   = (unsigned short*)(ws + (12u << 20));
  int*            deg   = (int*)  (ws + (16u << 20));
  unsigned*       g_u32 = (unsigned*)(ws + (17u << 20));

  hipLaunchKernelGGL(k_scanproj, dim3(5120), dim3(256), 0, stream,
                     x, W1a, u, adj, nbr, deg, g_u32);
  hipLaunchKernelGGL(k_gathA,    dim3(4096), dim3(256), 0, stream,
                     u, nbr, deg, mask, b1a, W2a, b2a, W1b, v);
  hipLaunchKernelGGL(k_gathB,    dim3(4096), dim3(256), 0, stream,
                     v, nbr, deg, mask, b1b, W2b, b2b, g_u32);
  hipLaunchKernelGGL(k_fin,      dim3(1),    dim3(320), 0, stream,
                     g_u32, Wfc, bfc, out);
}